// Round 1
// baseline (19058.252 us; speedup 1.0000x reference)
//
#include <hip/hip_runtime.h>
#include <hip/hip_bf16.h>
#include <math.h>

#define TSEQ 4096
#define EMBD 1024
#define HH   512
#define NTAGS 5
#define NGATE 2048
#define NEGV (-10000.0f)
#define START_TAG 3
#define STOP_TAG 4

__device__ __forceinline__ float sigm(float x){ return 1.0f/(1.0f+expf(-x)); }

// ---------------- init: prime h ping-pong + zero barrier counters ----------------
__global__ void k_init(const float* __restrict__ h0, float* __restrict__ hx, int* __restrict__ ctr){
  int tid = threadIdx.x;
  if (tid < 1024){
    int dir = tid >> 9, u = tid & 511;
    hx[(dir*2 + 0)*HH + u] = h0[dir*HH + u];
  }
  if (tid < 2) ctr[tid] = 0;
}

// ---------------- input projection GEMM (fp32, fused embedding gather + bias) ----
// A[dir][t][n] = sum_k W_ih[n][k] * emb[sent[t]][k] + b[n]
__global__ __launch_bounds__(256) void k_inproj(
    const int* __restrict__ sent, const float* __restrict__ emb,
    const float* __restrict__ Wf, const float* __restrict__ bf,
    const float* __restrict__ Wb, const float* __restrict__ bb,
    float* __restrict__ A){
  __shared__ __align__(16) float As[16][132];
  __shared__ __align__(16) float Bs[16][132];
  __shared__ int srow[128];
  const int tid = threadIdx.x;
  const int t0  = blockIdx.x * 128;
  const int ng0 = blockIdx.y * 128;
  const int dir = (ng0 >= NGATE) ? 1 : 0;
  const float* __restrict__ W    = dir ? Wb : Wf;
  const float* __restrict__ bias = dir ? bb : bf;
  const int n0 = ng0 & (NGATE - 1);
  if (tid < 128) srow[tid] = sent[t0 + tid];
  __syncthreads();
  const int lr = tid >> 2;          // loader row 0..63 (two passes)
  const int kq = (tid & 3) * 4;     // k sub-offset within 16
  const float* ea0 = emb + (size_t)srow[lr]      * EMBD + kq;
  const float* ea1 = emb + (size_t)srow[lr + 64] * EMBD + kq;
  const float* wb0 = W + (size_t)(n0 + lr)      * EMBD + kq;
  const float* wb1 = W + (size_t)(n0 + lr + 64) * EMBD + kq;
  const int tx = tid & 15, ty = tid >> 4;
  float acc[8][8];
  #pragma unroll
  for (int i = 0; i < 8; i++)
    #pragma unroll
    for (int j = 0; j < 8; j++) acc[i][j] = 0.f;

  for (int k0 = 0; k0 < EMBD; k0 += 16){
    float4 va0 = *(const float4*)(ea0 + k0);
    float4 va1 = *(const float4*)(ea1 + k0);
    float4 vb0 = *(const float4*)(wb0 + k0);
    float4 vb1 = *(const float4*)(wb1 + k0);
    As[kq+0][lr] = va0.x; As[kq+1][lr] = va0.y; As[kq+2][lr] = va0.z; As[kq+3][lr] = va0.w;
    As[kq+0][lr+64] = va1.x; As[kq+1][lr+64] = va1.y; As[kq+2][lr+64] = va1.z; As[kq+3][lr+64] = va1.w;
    Bs[kq+0][lr] = vb0.x; Bs[kq+1][lr] = vb0.y; Bs[kq+2][lr] = vb0.z; Bs[kq+3][lr] = vb0.w;
    Bs[kq+0][lr+64] = vb1.x; Bs[kq+1][lr+64] = vb1.y; Bs[kq+2][lr+64] = vb1.z; Bs[kq+3][lr+64] = vb1.w;
    __syncthreads();
    #pragma unroll
    for (int k = 0; k < 16; k++){
      float a[8], b[8];
      *(float4*)&a[0] = *(const float4*)&As[k][ty*8];
      *(float4*)&a[4] = *(const float4*)&As[k][ty*8 + 4];
      #pragma unroll
      for (int j = 0; j < 8; j++) b[j] = Bs[k][tx + 16*j];
      #pragma unroll
      for (int i = 0; i < 8; i++)
        #pragma unroll
        for (int j = 0; j < 8; j++)
          acc[i][j] = fmaf(a[i], b[j], acc[i][j]);
    }
    __syncthreads();
  }
  float bj[8];
  #pragma unroll
  for (int j = 0; j < 8; j++) bj[j] = bias[n0 + tx + 16*j];
  float* Abase = A + (size_t)dir * TSEQ * NGATE;
  #pragma unroll
  for (int i = 0; i < 8; i++){
    float* dst = Abase + (size_t)(t0 + ty*8 + i) * NGATE + n0 + tx;
    #pragma unroll
    for (int j = 0; j < 8; j++) dst[16*j] = acc[i][j] + bj[j];
  }
}

// ---------------- persistent BiLSTM recurrence ----------------
// 64 WGs: blocks 0..31 forward, 32..63 backward. WG w owns hidden units
// [16w,16w+16): 64 gate rows x 512 cols of W_hh kept in registers
// (64 f32/thread, 512 threads). h exchanged via global ping-pong buffer with
// agent-scope atomics; monotonic counter barrier (release add / acquire spin).
__global__ __launch_bounds__(512) void k_lstm(
    const float* __restrict__ Whf, const float* __restrict__ Whb,
    const float* __restrict__ c0,
    const float* __restrict__ A, float* __restrict__ hseq,
    float* __restrict__ hx, int* __restrict__ ctr){
  const int bid = blockIdx.x;
  const int dir = bid >> 5;
  const int w   = bid & 31;
  const int tid = threadIdx.x;
  const int r = tid >> 3, q = tid & 7;              // gate-row local, col octant
  const int R = (r >> 4)*HH + w*16 + (r & 15);      // global gate row (i,f,g,o blocks)
  const float* Wh = dir ? Whb : Whf;
  float wreg[64];
  {
    const float* wrow = Wh + (size_t)R*HH + q*64;
    #pragma unroll
    for (int j = 0; j < 16; j++){
      float4 v = *(const float4*)(wrow + 4*j);
      wreg[4*j+0] = v.x; wreg[4*j+1] = v.y; wreg[4*j+2] = v.z; wreg[4*j+3] = v.w;
    }
  }
  float creg = 0.f;
  if (tid < 16) creg = c0[dir*HH + w*16 + tid];
  __shared__ __align__(16) float4 hbuf[128];   // h, XOR-swizzled chunks
  __shared__ float gsh[64];
  const int hxbase = dir*2;

  for (int s = 0; s < TSEQ; s++){
    const int t = dir ? (TSEQ - 1 - s) : s;
    if (tid == 0 && s > 0){
      const int target = 32*s;
      while (__hip_atomic_load(&ctr[dir], __ATOMIC_ACQUIRE, __HIP_MEMORY_SCOPE_AGENT) < target)
        __builtin_amdgcn_s_sleep(1);
    }
    __syncthreads();
    {  // stage h into LDS (swizzled to spread ds_read_b128 bank groups)
      float v = __hip_atomic_load(&hx[(hxbase + (s & 1))*HH + tid],
                                  __ATOMIC_RELAXED, __HIP_MEMORY_SCOPE_AGENT);
      int c  = tid >> 2;
      int sc = c ^ ((c >> 4) & 7);
      ((float*)hbuf)[sc*4 + (tid & 3)] = v;
    }
    float a_r = 0.f;
    if (q == 0) a_r = A[((size_t)dir*TSEQ + t)*NGATE + R];   // prefetch, used post-matvec
    __syncthreads();
    float acc0 = 0.f, acc1 = 0.f, acc2 = 0.f, acc3 = 0.f;
    #pragma unroll
    for (int j = 0; j < 16; j++){
      float4 h4 = hbuf[(q*16 + j) ^ q];
      acc0 = fmaf(wreg[4*j+0], h4.x, acc0);
      acc1 = fmaf(wreg[4*j+1], h4.y, acc1);
      acc2 = fmaf(wreg[4*j+2], h4.z, acc2);
      acc3 = fmaf(wreg[4*j+3], h4.w, acc3);
    }
    float acc = (acc0 + acc1) + (acc2 + acc3);
    acc += __shfl_xor(acc, 1);
    acc += __shfl_xor(acc, 2);
    acc += __shfl_xor(acc, 4);
    if (q == 0) gsh[r] = acc + a_r;
    __syncthreads();
    if (tid < 16){
      const float gi = gsh[tid], gf = gsh[16 + tid], gg = gsh[32 + tid], go = gsh[48 + tid];
      const float c2 = sigm(gf)*creg + sigm(gi)*tanhf(gg);
      const float h2 = sigm(go)*tanhf(c2);
      creg = c2;
      const int idx = w*16 + tid;
      hseq[((size_t)dir*TSEQ + t)*HH + idx] = h2;
      __hip_atomic_store(&hx[(hxbase + ((s + 1) & 1))*HH + idx], h2,
                         __ATOMIC_RELAXED, __HIP_MEMORY_SCOPE_AGENT);
    }
    __syncthreads();
    if (tid == 0)
      __hip_atomic_fetch_add(&ctr[dir], 1, __ATOMIC_RELEASE, __HIP_MEMORY_SCOPE_AGENT);
  }
}

// ---------------- emission features: feats[t][n] = lstm_out[t] . W_out[n] + b ----
__global__ __launch_bounds__(64) void k_feats(
    const float* __restrict__ Wout, const float* __restrict__ bout,
    const float* __restrict__ hseq, float* __restrict__ feats){
  const int t = blockIdx.x, lane = threadIdx.x;
  const float* hf = hseq + (size_t)t*HH;
  const float* hb = hseq + (size_t)(TSEQ + t)*HH;
  float x[16];
  #pragma unroll
  for (int k = 0; k < 8; k++) x[k]     = hf[lane + 64*k];
  #pragma unroll
  for (int k = 0; k < 8; k++) x[8 + k] = hb[lane + 64*k];
  #pragma unroll
  for (int n = 0; n < NTAGS; n++){
    const float* wr = Wout + (size_t)n*(2*HH);
    float p = 0.f;
    #pragma unroll
    for (int k = 0; k < 8; k++) p = fmaf(x[k],     wr[lane + 64*k],      p);
    #pragma unroll
    for (int k = 0; k < 8; k++) p = fmaf(x[8 + k], wr[HH + lane + 64*k], p);
    #pragma unroll
    for (int d = 1; d < 64; d <<= 1) p += __shfl_xor(p, d);
    if (lane == 0) feats[t*8 + n] = p + bout[n];
  }
}

// ---------------- Viterbi forward + backtrack (1 wave) ----------------
// lane = to*8 + from (5x5 valid). First-max tie-break matches jnp.argmax.
__global__ __launch_bounds__(64) void k_viterbi(
    const float* __restrict__ trans, const float* __restrict__ feats,
    int* __restrict__ bpw, float* __restrict__ out){
  const int lane = threadIdx.x;
  const int to = lane >> 3, from = lane & 7;
  const bool v_to = (to < NTAGS), v_from = (from < NTAGS);
  const float tv = (v_to && v_from) ? trans[to*NTAGS + from] : -1e30f;
  float fv = (from == START_TAG) ? 0.f : NEGV;    // fv for my 'from' tag
  __shared__ float fsh[512];
  for (int t0 = 0; t0 < TSEQ; t0 += 64){
    __syncthreads();
    #pragma unroll
    for (int i = 0; i < 8; i++) fsh[lane + 64*i] = feats[t0*8 + lane + 64*i];
    __syncthreads();
    for (int i = 0; i < 64; i++){
      const int t = t0 + i;
      float bv = fv + tv; int bi = from;
      #pragma unroll
      for (int d = 1; d < 8; d <<= 1){
        float ov = __shfl_xor(bv, d);
        int   oi = __shfl_xor(bi, d);
        if (ov > bv || (ov == bv && oi < bi)){ bv = ov; bi = oi; }
      }
      float nf = bv + fsh[i*8 + to];       // new fv[to] (garbage for to>=5, discarded)
      int wv = 0;
      #pragma unroll
      for (int tt = 0; tt < 5; tt++) wv |= (__shfl(bi, tt*8) & 15) << (4*tt);
      if (lane == 0) bpw[t] = wv;
      float nfv = __shfl(nf, from*8);
      fv = v_from ? nfv : NEGV;
    }
  }
  // terminal: fv + trans[STOP][from]
  float bv = fv + (v_from ? trans[STOP_TAG*NTAGS + from] : -1e30f);
  int bi = from;
  #pragma unroll
  for (int d = 1; d < 8; d <<= 1){
    float ov = __shfl_xor(bv, d);
    int   oi = __shfl_xor(bi, d);
    if (ov > bv || (ov == bv && oi < bi)){ bv = ov; bi = oi; }
  }
  float score = __shfl(bv, 0);
  int btag = __shfl(bi, 0);
  if (lane == 0){ out[0] = score; out[TSEQ] = (float)btag; }   // out[1 + (T-1)]
  int tag = btag;
  for (int b = 63; b >= 0; b--){
    int v = bpw[b*64 + lane];
    for (int i = 63; i >= 0; i--){
      int t = b*64 + i;
      if (t == 0) break;                     // bpw[0] points at virtual START
      int wv2 = __shfl(v, i);
      int prev = (wv2 >> (tag*4)) & 15;
      if (lane == 0) out[t] = (float)prev;   // out[1 + (t-1)]
      tag = prev;
    }
  }
}

extern "C" void kernel_launch(void* const* d_in, const int* in_sizes, int n_in,
                              void* d_out, int out_size, void* d_ws, size_t ws_size,
                              hipStream_t stream) {
  const int*   sent = (const int*)  d_in[0];
  const float* emb  = (const float*)d_in[1];
  const float* Wihf = (const float*)d_in[2];
  const float* Whhf = (const float*)d_in[3];
  const float* bf_  = (const float*)d_in[4];
  const float* Wihb = (const float*)d_in[5];
  const float* Whhb = (const float*)d_in[6];
  const float* bb_  = (const float*)d_in[7];
  const float* Wout = (const float*)d_in[8];
  const float* bout = (const float*)d_in[9];
  const float* trans= (const float*)d_in[10];
  const float* h0   = (const float*)d_in[11];
  const float* c0   = (const float*)d_in[12];
  float* out = (float*)d_out;

  float* ws   = (float*)d_ws;
  float* A    = ws;                                  // [2][T][2048]
  float* hseq = A    + (size_t)2*TSEQ*NGATE;         // [2][T][512]
  float* hx   = hseq + (size_t)2*TSEQ*HH;            // [2][2][512] ping-pong
  float* fe   = hx   + 2048;                         // [T][8]
  int*   bpw  = (int*)(fe + (size_t)TSEQ*8);         // [T] packed nibbles
  int*   ctr  = bpw + TSEQ;                          // [2]

  k_init<<<1, 1024, 0, stream>>>(h0, hx, ctr);
  dim3 gg(TSEQ/128, 4096/128);
  k_inproj<<<gg, 256, 0, stream>>>(sent, emb, Wihf, bf_, Wihb, bb_, A);
  k_lstm<<<64, 512, 0, stream>>>(Whhf, Whhb, c0, A, hseq, hx, ctr);
  k_feats<<<TSEQ, 64, 0, stream>>>(Wout, bout, hseq, fe);
  k_viterbi<<<1, 64, 0, stream>>>(trans, fe, bpw, out);
}